// Round 2
// baseline (581.558 us; speedup 1.0000x reference)
//
#include <hip/hip_runtime.h>
#include <math.h>

#define B_ 256
#define N_ 4096
#define D_ 128
#define C_ 32

typedef float vf4 __attribute__((ext_vector_type(4)));

// ---------------------------------------------------------------------------
// K0 prep: per case row n compute
//   fwsp[n,d] = softplus(fw)           (row layout, for delta kernel)
//   w1t[d,n]  = wfw = fwsp * -|dw|     (TRANSPOSED, for act GEMM)
//   w2t[d,n]  = -2 * c * wfw           (TRANSPOSED)
//   t3[n]     = sum_d c^2 * wfw + bias (per-n constant)
// One 32-lane group per row; 8 rows / 256-thread block; N/8 = 512 blocks.
// ---------------------------------------------------------------------------
__global__ __launch_bounds__(256) void prep_kernel(
    const float* __restrict__ fwin, const float* __restrict__ dwin,
    const float* __restrict__ cases, const float* __restrict__ bias,
    float* __restrict__ fwsp, float* __restrict__ w1t,
    float* __restrict__ w2t, float* __restrict__ t3) {
  const int g = threadIdx.x >> 5;
  const int lane = threadIdx.x & 31;
  const int n = blockIdx.x * 8 + g;
  const int d0 = lane * 4;
  const size_t off = (size_t)n * D_ + d0;

  const vf4 x = *(const vf4*)(fwin + off);
  const vf4 w = *(const vf4*)(dwin + off);
  const vf4 c = *(const vf4*)(cases + off);

  vf4 sp, wfw, m2;
  float s = 0.f;
  #pragma unroll
  for (int k = 0; k < 4; ++k) {
    const float xv = x[k];
    const float spk = (xv > 20.f) ? xv : log1pf(expf(xv));
    const float wk = spk * (-fabsf(w[k]));
    sp[k] = spk;
    wfw[k] = wk;
    m2[k] = -2.f * c[k] * wk;
    s += c[k] * c[k] * wk;
  }
  *(vf4*)(fwsp + off) = sp;
  #pragma unroll
  for (int k = 0; k < 4; ++k) {
    w1t[(size_t)(d0 + k) * N_ + n] = wfw[k];
    w2t[(size_t)(d0 + k) * N_ + n] = m2[k];
  }
  #pragma unroll
  for (int o = 16; o > 0; o >>= 1)
    s += __shfl_xor(s, o, 32);
  if (lane == 0) t3[n] = s + bias[n];
}

// ---------------------------------------------------------------------------
// K_delta: PURE streaming kernel. delta = (q-c)^2 * fwsp. No reductions,
// no transcendentals, no scalar stores — should run at the write ceiling.
// Grid: 256 nc x 8 bc = 2048 blocks, 256 thr. Group g owns rows nc*16+g,+8;
// case-side regs loaded once, reused over 32 b. Wave stores 1KB contiguous.
// blockIdx%8 == nc%8 -> same-n blocks share an XCD L2.
// ---------------------------------------------------------------------------
__global__ __launch_bounds__(256) void delta_kernel(
    const float* __restrict__ q,      // [B, D]
    const float* __restrict__ cases,  // [N, D]
    const float* __restrict__ fwsp,   // [N, D]
    float* __restrict__ delta_out) {  // [B, N, D]
  const int nc   = blockIdx.x & 255;
  const int bc   = blockIdx.x >> 8;
  const int g    = threadIdx.x >> 5;
  const int lane = threadIdx.x & 31;
  const int d0   = lane * 4;
  const int b0   = bc * 32;

  int n[2];
  vf4 cv[2], fv[2];
  n[0] = nc * 16 + g;
  n[1] = n[0] + 8;
  #pragma unroll
  for (int j = 0; j < 2; ++j) {
    const size_t off = (size_t)n[j] * D_ + d0;
    cv[j] = *(const vf4*)(cases + off);
    fv[j] = *(const vf4*)(fwsp + off);
  }

  #pragma unroll 4
  for (int bi = 0; bi < 32; ++bi) {
    const int b = b0 + bi;
    const vf4 qv = *(const vf4*)(q + (size_t)b * D_ + d0);
    #pragma unroll
    for (int j = 0; j < 2; ++j) {
      const vf4 dd = qv - cv[j];
      const vf4 dl = (dd * dd) * fv[j];
      __builtin_nontemporal_store(
          dl, (vf4*)(delta_out + ((size_t)b * N_ + n[j]) * D_ + d0));
    }
  }
}

// ---------------------------------------------------------------------------
// K_act: case_act[b,n] = sum_k q^2[b,k]*w1t[k,n] + q[b,k]*w2t[k,n] + t3[n]
//        act = sigmoid(case_act)
// Grid: 32 bc x 16 nc = 512 blocks, 256 thr = 4 k-teams x 64 n-lanes.
// Team kq covers k in [kq*32, kq*32+32) for ALL 8 b; lane owns vf4 of n.
// w-tile elements read once per block (coalesced [k][n] rows, L2-resident);
// partials combined via LDS; team 0 applies sigmoid + coalesced act store.
// ---------------------------------------------------------------------------
__global__ __launch_bounds__(256) void act_kernel(
    const float* __restrict__ q,    // [B, D]
    const float* __restrict__ w1t,  // [D, N]
    const float* __restrict__ w2t,  // [D, N]
    const float* __restrict__ t3,   // [N]
    float* __restrict__ act) {      // [B, N]
  const int bc = blockIdx.x >> 4;    // 0..31
  const int nc = blockIdx.x & 15;    // 0..15
  const int kq = threadIdx.x >> 6;   // 0..3
  const int nl = threadIdx.x & 63;   // 0..63
  const int n0 = nc * 256 + nl * 4;
  const int b0 = bc * 8;

  vf4 acc[8];
  #pragma unroll
  for (int b = 0; b < 8; ++b) acc[b] = (vf4)(0.f);

  #pragma unroll 4
  for (int kk = 0; kk < 32; ++kk) {
    const int k = kq * 32 + kk;
    const vf4 w1 = *(const vf4*)(w1t + (size_t)k * N_ + n0);
    const vf4 w2 = *(const vf4*)(w2t + (size_t)k * N_ + n0);
    #pragma unroll
    for (int b = 0; b < 8; ++b) {
      const float a = q[(size_t)(b0 + b) * D_ + k];  // lane-uniform -> scalar
      acc[b] += (a * a) * w1 + a * w2;
    }
  }

  __shared__ vf4 part[3][8][64];
  if (kq > 0) {
    #pragma unroll
    for (int b = 0; b < 8; ++b) part[kq - 1][b][nl] = acc[b];
  }
  __syncthreads();
  if (kq == 0) {
    const vf4 tv = *(const vf4*)(t3 + n0);
    #pragma unroll
    for (int t = 0; t < 3; ++t)
      #pragma unroll
      for (int b = 0; b < 8; ++b) acc[b] += part[t][b][nl];
    #pragma unroll
    for (int b = 0; b < 8; ++b) {
      const vf4 ca = acc[b] + tv;
      vf4 av;
      #pragma unroll
      for (int k = 0; k < 4; ++k)
        av[k] = 1.f / (1.f + __expf(-ca[k]));
      *(vf4*)(act + (size_t)(b0 + b) * N_ + n0) = av;
    }
  }
}

// ---------------------------------------------------------------------------
// K_finish: per-b activation sum + y_hat in ONE pass over act.
// ---------------------------------------------------------------------------
__global__ __launch_bounds__(1024) void finish_kernel(
    const float* __restrict__ act,      // [B, N]
    const float* __restrict__ targets,  // [N, C]
    float* __restrict__ y) {            // [B, C]
  const int b = blockIdx.x;
  const int c = threadIdx.x & 31;
  const int g = threadIdx.x >> 5;       // 0..31
  float ys = 0.f, ss = 0.f;
  for (int n0 = g * 4; n0 < N_; n0 += 128) {
    const vf4 a = *(const vf4*)(act + (size_t)b * N_ + n0);
    ys += a.x * targets[(size_t)(n0 + 0) * C_ + c];
    ys += a.y * targets[(size_t)(n0 + 1) * C_ + c];
    ys += a.z * targets[(size_t)(n0 + 2) * C_ + c];
    ys += a.w * targets[(size_t)(n0 + 3) * C_ + c];
    ss += (a.x + a.y) + (a.z + a.w);
  }
  __shared__ float sm_y[32][33];
  __shared__ float sm_s[32];
  sm_y[g][c] = ys;
  if (c == 0) sm_s[g] = ss;
  __syncthreads();
  if (g == 0) {
    float t = 0.f, s = 0.f;
    #pragma unroll
    for (int k = 0; k < 32; ++k) { t += sm_y[k][c]; s += sm_s[k]; }
    y[(size_t)b * C_ + c] = t / (s + 0.01f);
  }
}

// ---------------------------------------------------------------------------
extern "C" void kernel_launch(void* const* d_in, const int* in_sizes, int n_in,
                              void* d_out, int out_size, void* d_ws, size_t ws_size,
                              hipStream_t stream) {
  const float* queries = (const float*)d_in[0];   // [B, D]
  const float* cases   = (const float*)d_in[1];   // [N, D]
  const float* targets = (const float*)d_in[2];   // [N, C]
  const float* fwin    = (const float*)d_in[3];   // [N, D]
  const float* dwin    = (const float*)d_in[4];   // [N, D]
  const float* bias    = (const float*)d_in[5];   // [N]

  float* out   = (float*)d_out;
  float* y_hat = out;                              // [B, C]
  float* act   = out + (size_t)B_ * C_;            // [B, N]
  float* delta = act + (size_t)B_ * N_;            // [B, N, D]

  float* fwsp = (float*)d_ws;                      // [N, D]
  float* w1t  = fwsp + (size_t)N_ * D_;            // [D, N]
  float* w2t  = w1t + (size_t)D_ * N_;             // [D, N]
  float* t3   = w2t + (size_t)D_ * N_;             // [N]

  prep_kernel<<<N_ / 8, 256, 0, stream>>>(fwin, dwin, cases, bias,
                                          fwsp, w1t, w2t, t3);
  delta_kernel<<<2048, 256, 0, stream>>>(queries, cases, fwsp, delta);
  act_kernel<<<512, 256, 0, stream>>>(queries, w1t, w2t, t3, act);
  finish_kernel<<<B_, 1024, 0, stream>>>(act, targets, y_hat);
}